// Round 9
// baseline (385.676 us; speedup 1.0000x reference)
//
#include <hip/hip_runtime.h>
#include <hip/hip_bf16.h>
#include <stdint.h>
#include <math.h>

#define B_ 2
#define S_ 2048
#define E_ 2048
#define H_ 16
#define D_ 128
#define M_ (B_*S_)

// 1/sqrt(128) * log2(e): folded into Q by the Q-GEMM epilogue so the
// attention softmax runs in the log2 domain with a bare v_exp_f32.
#define QSCALE 0.1275174308f

typedef _Float16 half8 __attribute__((ext_vector_type(8)));
typedef _Float16 half4 __attribute__((ext_vector_type(4)));
typedef float    floatx4 __attribute__((ext_vector_type(4)));

// ---------------------------------------------------------------------------
// async global->LDS, 16B per lane. LDS dest must be wave-uniform base; HW
// writes lane L at base + L*16.
__device__ __forceinline__ void async_copy16(const void* g, void* lds_base) {
    __builtin_amdgcn_global_load_lds(
        (__attribute__((address_space(1))) void*)(uintptr_t)g,
        (__attribute__((address_space(3))) void*)(uint32_t)(uintptr_t)lds_base,
        16, 0, 0);
}

// ---------------------------------------------------------------------------
// DPP 16-lane row reductions (pure VALU — no ds_swizzle, no lgkmcnt chains).
template<int CTRL>
__device__ __forceinline__ float dpp_mv(float x) {
    return __int_as_float(__builtin_amdgcn_update_dpp(
        0, __float_as_int(x), CTRL, 0xF, 0xF, true));
}
__device__ __forceinline__ float row_max16(float x) {
    x = fmaxf(x, dpp_mv<0xB1>(x));
    x = fmaxf(x, dpp_mv<0x4E>(x));
    x = fmaxf(x, dpp_mv<0x124>(x));
    x = fmaxf(x, dpp_mv<0x128>(x));
    return x;
}
__device__ __forceinline__ float row_sum16(float x) {
    x += dpp_mv<0xB1>(x);
    x += dpp_mv<0x4E>(x);
    x += dpp_mv<0x124>(x);
    x += dpp_mv<0x128>(x);
    return x;
}
// native 2^x
__device__ __forceinline__ float fexp2(float x) {
    float r; __asm__("v_exp_f32 %0, %1" : "=v"(r) : "v"(x)); return r;
}

// ---------------------------------------------------------------------------
// fused fp32 -> fp16 cast, zero wasted blocks: grid (4096,1,6);
// z=0,1 -> X halves; z=2..5 -> the four weights.
__global__ __launch_bounds__(256) void cast_all(
    const float* __restrict__ X,  const float* __restrict__ Wq,
    const float* __restrict__ Wk, const float* __restrict__ Wv,
    const float* __restrict__ Wo,
    _Float16* __restrict__ Xh,  _Float16* __restrict__ Wqh,
    _Float16* __restrict__ Wkh, _Float16* __restrict__ Wvh,
    _Float16* __restrict__ Woh)
{
    const int z = blockIdx.z;
    const float* in; _Float16* out; size_t off = 0;
    switch (z) {
        case 0: in = X;  out = Xh;  off = 0;        break;
        case 1: in = X;  out = Xh;  off = 1048576;  break;   // ME4/2
        case 2: in = Wq; out = Wqh; break;
        case 3: in = Wk; out = Wkh; break;
        case 4: in = Wv; out = Wvh; break;
        default: in = Wo; out = Woh; break;
    }
    size_t i = off + (size_t)blockIdx.x * 256 + threadIdx.x;
    floatx4 v = ((const floatx4*)in)[i];
    ((half4*)out)[i] = __builtin_convertvector(v, half4);
}

// ---------------------------------------------------------------------------
// Free-flow pipelined GEMM, templated on BK for occupancy control:
//  - BK=32: ring buffer 2x16KB = 32KB LDS -> 4 blocks/CU (launch_bounds
//    (256,4) caps VGPR<=128). Doubles barrier count (64 tiles) but each
//    barrier is decorrelated across 4 independent blocks per CU — the only
//    lever that has paid on this kernel (round 6: 1->2 blocks +6.5%).
//  - BK=64: the proven round-6/8 configuration (2 blocks/CU), kept for Wo.
// Swizzle: BK=64: granule ^= row&7 (proven, 0 conflicts).
//          BK=32: granule ^= (row>>1)&3 (4 granules/row at 64B row stride;
//          fragment reads land 2 rows/bank-quad = free 2-way).
//          Diagnostic: SQ_LDS_BANK_CONFLICT.
template<int BK>
__device__ __forceinline__ int swz(int g, int row) {
    if constexpr (BK == 64) return g ^ (row & 7);
    else                    return g ^ ((row >> 1) & 3);
}

template<int BK>
__device__ __forceinline__ void stage_mat(
    const _Float16* __restrict__ gsrc, int ldk,
    _Float16* lbase, int wave, int lane)
{
    constexpr int GPR   = BK / 8;               // 16B granules per row
    constexpr int CALLS = (128 * GPR) / 256;    // gload_lds insts per matrix
#pragma unroll
    for (int i = 0; i < CALLS; ++i) {
        int slot = i*256 + wave*64 + lane;
        int row  = slot / GPR;
        int sg   = swz<BK>(slot % GPR, row);    // inverse swizzle on source
        async_copy16(gsrc + (size_t)row * ldk + sg * 8,
                     lbase + (size_t)(i*256 + wave*64) * 8);
    }
}

template<bool BIAS, typename OutT, int NW, bool TRV, int BK>
__global__ __launch_bounds__(256, BK == 32 ? 4 : 2) void gemm_bt(
    const _Float16* __restrict__ A,
    const _Float16* __restrict__ W0, const _Float16* __restrict__ W1,
    const _Float16* __restrict__ W2,
    OutT* __restrict__ C0, OutT* __restrict__ C1, OutT* __restrict__ C2,
    const float* __restrict__ bias, int M, int N, int K)
{
    constexpr int GB = 2 * 128 * BK;            // f16 elems per ring buffer
    constexpr int KG = BK / 32;                 // MFMA k-steps per tile

    const _Float16* W = W0; OutT* C = C0;
    if (NW > 1) {
        if (blockIdx.y == 1) { W = W1; C = C1; }
        else if (blockIdx.y == 2) { W = W2; C = C2; }
    }
    __shared__ __align__(16) _Float16 sm[2 * GB];

    const int tid  = threadIdx.x;
    const int lane = tid & 63;
    const int wave = tid >> 6;                        // 0..3
    const int wm = wave >> 1, wn = wave & 1;          // 2x2 waves, 64x64 each
    const int fr = lane & 15, fg = lane >> 4;

    const int bx = blockIdx.x;
    const int n_tile = bx & 15;                       // XCD-chunk: B panels/XCD L2
    const int m_tile = bx >> 4;
    const int m0 = m_tile * 128;
    const int n0 = n_tile * 128;

    const int NT = K / BK;

    // ---- prologue: stage tile 0 into buf 0 --------------------------------
    stage_mat<BK>(A + (size_t)m0 * K, K, &sm[0],        wave, lane);
    stage_mat<BK>(W + (size_t)n0 * K, K, &sm[128*BK],   wave, lane);

    floatx4 acc[4][4] = {};

    for (int t = 0; t < NT; ++t) {
        // ---- tile boundary: tile t's loads are the only outstanding ------
        __asm__ __volatile__("s_waitcnt vmcnt(0)" ::: "memory");
        __builtin_amdgcn_sched_barrier(0);
        __builtin_amdgcn_s_barrier();      // t landed; buf[(t+1)&1] reads done
        __builtin_amdgcn_sched_barrier(0);

        const _Float16* Ab = &sm[(t & 1) * GB];
        const _Float16* Bb = Ab + 128*BK;

        // ---- issue tile t+1 staging first (max in-flight cover) ----------
        if (t + 1 < NT) {
            _Float16* pab = &sm[((t + 1) & 1) * GB];
            stage_mat<BK>(A + (size_t)m0 * K + (t + 1)*BK, K, pab,          wave, lane);
            stage_mat<BK>(W + (size_t)n0 * K + (t + 1)*BK, K, pab + 128*BK, wave, lane);
        }

        // ---- fragment loads (compiler-scheduled, fine-grained lgkmcnt) ---
        half8 af[4][KG], bf[4][KG];
#pragma unroll
        for (int mt = 0; mt < 4; ++mt)
#pragma unroll
            for (int kk = 0; kk < KG; ++kk) {
                int row = wm*64 + mt*16 + fr;
                int g = swz<BK>(kk*4 + fg, row);
                af[mt][kk] = *(const half8*)&Ab[row*BK + g*8];
            }
#pragma unroll
        for (int nt = 0; nt < 4; ++nt)
#pragma unroll
            for (int kk = 0; kk < KG; ++kk) {
                int row = wn*64 + nt*16 + fr;
                int g = swz<BK>(kk*4 + fg, row);
                bf[nt][kk] = *(const half8*)&Bb[row*BK + g*8];
            }

        // ---- MFMA ---------------------------------------------------------
        __builtin_amdgcn_s_setprio(1);
#pragma unroll
        for (int kk = 0; kk < KG; ++kk)
#pragma unroll
            for (int nt = 0; nt < 4; ++nt)
#pragma unroll
                for (int mt = 0; mt < 4; ++mt)
                    acc[mt][nt] = __builtin_amdgcn_mfma_f32_16x16x32_f16(
                        af[mt][kk], bf[nt][kk], acc[mt][nt], 0, 0, 0);
        __builtin_amdgcn_s_setprio(0);
    }

    // ---- epilogue ---------------------------------------------------------
    if (TRV && NW > 1 && blockIdx.y == 2) {
        // write V output directly as Vt[bh][d][s]; r-values are s-contiguous
        _Float16* Vt = (_Float16*)C;
#pragma unroll
        for (int mt = 0; mt < 4; ++mt)
#pragma unroll
            for (int nt = 0; nt < 4; ++nt) {
                int col  = n0 + wn*64 + nt*16 + fr;       // h*128 + d
                int row0 = m0 + wm*64 + mt*16 + fg*4;     // b*2048 + s
                int bq = row0 >> 11, s0 = row0 & 2047;
                int hq = col >> 7,  dq = col & 127;
                half4 v;
#pragma unroll
                for (int r = 0; r < 4; ++r) v[r] = (_Float16)acc[mt][nt][r];
                *(half4*)&Vt[(((size_t)(bq*16 + hq) * 128 + dq) << 11) + s0] = v;
            }
    } else {
        const float qs = (NW > 1 && blockIdx.y == 0) ? QSCALE : 1.f;
#pragma unroll
        for (int mt = 0; mt < 4; ++mt)
#pragma unroll
            for (int nt = 0; nt < 4; ++nt) {
                int col = n0 + wn*64 + nt*16 + fr;
                float bv = BIAS ? bias[col] : 0.f;
#pragma unroll
                for (int r = 0; r < 4; ++r) {
                    int row = m0 + wm*64 + mt*16 + fg*4 + r;
                    C[(size_t)row * N + col] = (OutT)(acc[mt][nt][r] * qs + bv);
                }
            }
    }
}

// ---------------------------------------------------------------------------
// Block-cooperative causal flash attention (round-8 version, unchanged).
// Complementary co-residency: pairs (j, 15-j) share a CU -> per-CU fixed
// cost uniform at 49 iteration-units.
__global__ __launch_bounds__(256, 2) void attn_causal_coop(
    const _Float16* __restrict__ Q, const _Float16* __restrict__ K,
    const _Float16* __restrict__ Vt, _Float16* __restrict__ O)
{
    const int n   = blockIdx.x;
    const int xcd = n & 7;
    const int idx = n >> 3;                    // 0..63
    const int bh  = xcd * 4 + (idx >> 4);      // 4 heads per XCD
    const int j0  = idx & 15;
    const int j   = (idx >> 5) ? 15 - j0 : j0; // complementary pairing
    const int b = bh >> 4, h = bh & 15;
    const int tid = threadIdx.x, lane = tid & 63, wave = tid >> 6;
    const int fr = lane & 15, fg = lane >> 4;

    __shared__ __align__(16) _Float16 Ks[2][64*128];  // 32KB, swizzled, dbuf
    __shared__ __align__(16) _Float16 Vs[2][128*64];  // 32KB, swizzled, dbuf
    __shared__ __align__(16) _Float16 Ps[4][32*64];   // 16KB, swizzled strips

    const int rhi = (31 - j) * 64 + wave * 16;   // this wave's hi-panel rows
    const int rlo = j * 64 + wave * 16;          // this wave's lo-panel rows
    const int nkt = 32 - j;                      // k-tiles of 64

    // Q fragments: A[m=fr][k=fg*8+..], mt: 0=hi panel, 1=lo panel
    half8 qf[2][4];
    {
        const _Float16* qb0 = Q + ((size_t)(b*S_) + rhi) * E_ + h*D_;
        const _Float16* qb1 = Q + ((size_t)(b*S_) + rlo) * E_ + h*D_;
#pragma unroll
        for (int kk = 0; kk < 4; ++kk) {
            qf[0][kk] = *(const half8*)&qb0[(size_t)fr * E_ + kk*32 + fg*8];
            qf[1][kk] = *(const half8*)&qb1[(size_t)fr * E_ + kk*32 + fg*8];
        }
    }

    float m_i[2][4], l_i[2][4];
    floatx4 o[2][8] = {};
#pragma unroll
    for (int mt = 0; mt < 2; ++mt)
#pragma unroll
        for (int r = 0; r < 4; ++r) { m_i[mt][r] = -INFINITY; l_i[mt][r] = 0.f; }

    const _Float16* kg = K + (size_t)(b*S_) * E_ + h*D_;
    const _Float16* vg = Vt + (size_t)bh * D_ * S_;
    _Float16* ps = &Ps[wave][0];

    // ---- prologue: stage K[0], V[0] into buffer 0 -------------------------
#pragma unroll
    for (int q = 0; q < 4; ++q) {
        int G = q*256 + tid;
        { int row = G >> 4, slot = G & 15;
          int c = slot ^ (row & 7);
          async_copy16(kg + (size_t)row * E_ + c*8, &Ks[0][(q*256 + wave*64) * 8]); }
        { int row = G >> 3, slot = G & 7;
          int c = slot ^ (row & 7);
          async_copy16(vg + (size_t)row * S_ + c*8, &Vs[0][(q*256 + wave*64) * 8]); }
    }

    for (int jt = 0; jt < nkt; ++jt) {
        // ---- tile top: own jt loads landed; barrier makes all visible ----
        __asm__ __volatile__("s_waitcnt vmcnt(0)" ::: "memory");
        __builtin_amdgcn_sched_barrier(0);
        __builtin_amdgcn_s_barrier();
        __builtin_amdgcn_sched_barrier(0);

        const int cur = jt & 1, nxt = cur ^ 1;

        // ---- issue jt+1 staging (in flight across the whole tile) --------
        if (jt + 1 < nkt) {
#pragma unroll
            for (int q = 0; q < 4; ++q) {
                int G = q*256 + tid;
                { int row = G >> 4, slot = G & 15;
                  int c = slot ^ (row & 7);
                  async_copy16(kg + (size_t)((jt+1)*64 + row) * E_ + c*8,
                               &Ks[nxt][(q*256 + wave*64) * 8]); }
                { int row = G >> 3, slot = G & 7;
                  int c = slot ^ (row & 7);
                  async_copy16(vg + (size_t)row * S_ + (jt+1)*64 + c*8,
                               &Vs[nxt][(q*256 + wave*64) * 8]); }
            }
        }

        const bool lo_act = (jt <= j);
        const _Float16* kt = &Ks[cur][0];
        const _Float16* vt = &Vs[cur][0];

        // ---- S = Q K^T (log2-domain logits: Q carries 1/sqrt(D)*log2e) ---
        floatx4 sacc[2][4] = {};
#pragma unroll
        for (int kk = 0; kk < 4; ++kk) {
            half8 bf[4];
#pragma unroll
            for (int nt = 0; nt < 4; ++nt)
                bf[nt] = *(const half8*)
                    &kt[(nt*16 + fr)*128 + (((kk*4 + fg) ^ (fr & 7)) * 8)];
#pragma unroll
            for (int nt = 0; nt < 4; ++nt)
                sacc[0][nt] = __builtin_amdgcn_mfma_f32_16x16x32_f16(
                    qf[0][kk], bf[nt], sacc[0][nt], 0, 0, 0);
            if (lo_act) {
#pragma unroll
                for (int nt = 0; nt < 4; ++nt)
                    sacc[1][nt] = __builtin_amdgcn_mfma_f32_16x16x32_f16(
                        qf[1][kk], bf[nt], sacc[1][nt], 0, 0, 0);
            }
        }

        // ---- online softmax (log2 domain, DPP reductions, defer-max) -----
        const int kc0 = jt*64 + fr;
#pragma unroll
        for (int mt = 0; mt < 2; ++mt) {
            if (mt == 1 && !lo_act) continue;
            const bool diag = mt ? (jt == j) : (jt == nkt - 1);
            const int qr0 = (mt ? rlo : rhi) + fg*4;
            float mx[4];
#pragma unroll
            for (int r = 0; r < 4; ++r) {
                float m0v;
                if (diag) {
                    m0v = -INFINITY;
#pragma unroll
                    for (int nt = 0; nt < 4; ++nt) {
                        float s = sacc[mt][nt][r];
                        s = (kc0 + nt*16 <= qr0 + r) ? s : -INFINITY;
                        sacc[mt][nt][r] = s;
                        m0v = fmaxf(m0v, s);
                    }
                } else {
                    m0v = fmaxf(fmaxf(sacc[mt][0][r], sacc[mt][1][r]),
                                fmaxf(sacc[mt][2][r], sacc[mt][3][r]));
                }
                mx[r] = row_max16(m0v);
            }
            bool grow = false;
#pragma unroll
            for (int r = 0; r < 4; ++r)
                grow = grow || (mx[r] > m_i[mt][r] + 8.f);
            if (__any(grow)) {                 // rare after warm-up (T13)
                float alpha[4];
#pragma unroll
                for (int r = 0; r < 4; ++r) {
                    float mnew = fmaxf(m_i[mt][r], mx[r]);
                    alpha[r] = (m_i[mt][r] == -INFINITY) ? 0.f
                                                         : fexp2(m_i[mt][r] - mnew);
                    l_i[mt][r] *= alpha[r];
                    m_i[mt][r] = mnew;
                }
#pragma unroll
                for (int dt = 0; dt < 8; ++dt)
#pragma unroll
                    for (int r = 0; r < 4; ++r) o[mt][dt][r] *= alpha[r];
            }
#pragma unroll
            for (int r = 0; r < 4; ++r) {
                float rs = 0.f;
#pragma unroll
                for (int nt = 0; nt < 4; ++nt) {
                    float p = fexp2(sacc[mt][nt][r] - m_i[mt][r]); // <= 2^8
                    sacc[mt][nt][r] = p;
                    rs += p;
                }
                rs = row_sum16(rs);
                l_i[mt][r] += rs;
            }
            // P: C-layout -> A-layout, wave-private swizzled strip
#pragma unroll
            for (int nt = 0; nt < 4; ++nt)
#pragma unroll
                for (int r = 0; r < 4; ++r) {
                    int q  = mt*16 + fg*4 + r;
                    int gl = nt*2 + (fr >> 3);
                    ps[q*64 + ((gl ^ (q & 7)) << 3) + (fr & 7)]
                        = (_Float16)sacc[mt][nt][r];
                }
        }
        __asm__ __volatile__("s_waitcnt lgkmcnt(0)" ::: "memory");
        __builtin_amdgcn_sched_barrier(0);

        // ---- O += P · V (wave-private P; Vs staged a full tile ago) ------
#pragma unroll
        for (int kk = 0; kk < 2; ++kk) {
            half8 pf0 = *(const half8*)
                &ps[(fr)*64 + (((kk*4 + fg) ^ (fr & 7)) << 3)];
            half8 pf1 = *(const half8*)
                &ps[(16 + fr)*64 + (((kk*4 + fg) ^ (fr & 7)) << 3)];
#pragma unroll
            for (int dt = 0; dt < 8; ++dt) {
                half8 vf = *(const half8*)
                    &vt[(dt*16 + fr)*64 + (((kk*4 + fg) ^ (fr & 7)) * 8)];
                o[0][dt] = __builtin_amdgcn_mfma_f32_16x16x32_f16(
                    pf0, vf, o[0][dt], 0, 0, 0);
                if (lo_act)
                    o[1][dt] = __builtin_amdgcn_mfma_f32_16x16x32_f16(
                        pf1, vf, o[1][dt], 0, 0, 0);
            }
        }
    }

    // ---- epilogue ---------------------------------------------------------
#pragma unroll
    for (int mt = 0; mt < 2; ++mt) {
        const int rbase = mt ? rlo : rhi;
        _Float16* ob = O + ((size_t)(b*S_) + rbase) * E_ + h*D_;
#pragma unroll
        for (int r = 0; r < 4; ++r) {
            float inv = 1.f / l_i[mt][r];
#pragma unroll
            for (int dt = 0; dt < 8; ++dt)
                ob[(size_t)(fg*4 + r) * E_ + dt*16 + fr] = (_Float16)(o[mt][dt][r] * inv);
        }
    }
}

// ---------------------------------------------------------------------------
extern "C" void kernel_launch(void* const* d_in, const int* in_sizes, int n_in,
                              void* d_out, int out_size, void* d_ws, size_t ws_size,
                              hipStream_t stream) {
    const float* X  = (const float*)d_in[0];
    const float* Wq = (const float*)d_in[1];
    const float* Wk = (const float*)d_in[2];
    const float* Wv = (const float*)d_in[3];
    const float* Wo = (const float*)d_in[4];
    const float* bo = (const float*)d_in[5];
    float* out = (float*)d_out;

    const size_t ME = (size_t)M_ * E_;   // 8,388,608
    const size_t EE = (size_t)E_ * E_;   // 4,194,304
    _Float16* ws  = (_Float16*)d_ws;
    _Float16* Xh  = ws;
    _Float16* Wqh = Xh  + ME;
    _Float16* Wkh = Wqh + EE;
    _Float16* Wvh = Wkh + EE;
    _Float16* Woh = Wvh + EE;
    _Float16* Qh  = Woh + EE;
    _Float16* Kh  = Qh  + ME;
    _Float16* Vth = Kh  + ME;   // V-GEMM writes Vt layout directly
    _Float16* Oh  = Xh;         // Xh dead after the QKV GEMMs

    cast_all<<<dim3(4096, 1, 6), dim3(256), 0, stream>>>(
        X, Wq, Wk, Wv, Wo, Xh, Wqh, Wkh, Wvh, Woh);

    gemm_bt<false, _Float16, 3, true, 32><<<dim3(512, 3), dim3(256), 0, stream>>>(
        Xh, Wqh, Wkh, Wvh, Qh, Kh, Vth, nullptr, M_, E_, E_);

    attn_causal_coop<<<dim3(512), dim3(256), 0, stream>>>(Qh, Kh, Vth, Oh);

    gemm_bt<true, float, 1, false, 64><<<dim3(512, 1), dim3(256), 0, stream>>>(
        Oh, Woh, nullptr, nullptr, out, nullptr, nullptr, bo, M_, E_, E_);
}

// Round 10
// 355.516 us; speedup vs baseline: 1.0848x; 1.0848x over previous
//
#include <hip/hip_runtime.h>
#include <hip/hip_bf16.h>
#include <stdint.h>
#include <math.h>

#define B_ 2
#define S_ 2048
#define E_ 2048
#define H_ 16
#define D_ 128
#define M_ (B_*S_)

// 1/sqrt(128) * log2(e): folded into Q by the Q-GEMM epilogue so the
// attention softmax runs in the log2 domain with a bare v_exp_f32.
#define QSCALE 0.1275174308f

typedef _Float16 half8 __attribute__((ext_vector_type(8)));
typedef _Float16 half4 __attribute__((ext_vector_type(4)));
typedef float    floatx4 __attribute__((ext_vector_type(4)));

// ---------------------------------------------------------------------------
// async global->LDS, 16B per lane. LDS dest must be wave-uniform base; HW
// writes lane L at base + L*16.
__device__ __forceinline__ void async_copy16(const void* g, void* lds_base) {
    __builtin_amdgcn_global_load_lds(
        (__attribute__((address_space(1))) void*)(uintptr_t)g,
        (__attribute__((address_space(3))) void*)(uint32_t)(uintptr_t)lds_base,
        16, 0, 0);
}

// ---------------------------------------------------------------------------
// DPP 16-lane row reductions (pure VALU — no ds_swizzle, no lgkmcnt chains).
template<int CTRL>
__device__ __forceinline__ float dpp_mv(float x) {
    return __int_as_float(__builtin_amdgcn_update_dpp(
        0, __float_as_int(x), CTRL, 0xF, 0xF, true));
}
__device__ __forceinline__ float row_max16(float x) {
    x = fmaxf(x, dpp_mv<0xB1>(x));
    x = fmaxf(x, dpp_mv<0x4E>(x));
    x = fmaxf(x, dpp_mv<0x124>(x));
    x = fmaxf(x, dpp_mv<0x128>(x));
    return x;
}
__device__ __forceinline__ float row_sum16(float x) {
    x += dpp_mv<0xB1>(x);
    x += dpp_mv<0x4E>(x);
    x += dpp_mv<0x124>(x);
    x += dpp_mv<0x128>(x);
    return x;
}
// native 2^x
__device__ __forceinline__ float fexp2(float x) {
    float r; __asm__("v_exp_f32 %0, %1" : "=v"(r) : "v"(x)); return r;
}

// ---------------------------------------------------------------------------
// fused fp32 -> fp16 cast, zero wasted blocks: grid (4096,1,6);
// z=0,1 -> X halves; z=2..5 -> the four weights.
__global__ __launch_bounds__(256) void cast_all(
    const float* __restrict__ X,  const float* __restrict__ Wq,
    const float* __restrict__ Wk, const float* __restrict__ Wv,
    const float* __restrict__ Wo,
    _Float16* __restrict__ Xh,  _Float16* __restrict__ Wqh,
    _Float16* __restrict__ Wkh, _Float16* __restrict__ Wvh,
    _Float16* __restrict__ Woh)
{
    const int z = blockIdx.z;
    const float* in; _Float16* out; size_t off = 0;
    switch (z) {
        case 0: in = X;  out = Xh;  off = 0;        break;
        case 1: in = X;  out = Xh;  off = 1048576;  break;   // ME4/2
        case 2: in = Wq; out = Wqh; break;
        case 3: in = Wk; out = Wkh; break;
        case 4: in = Wv; out = Wvh; break;
        default: in = Wo; out = Woh; break;
    }
    size_t i = off + (size_t)blockIdx.x * 256 + threadIdx.x;
    floatx4 v = ((const floatx4*)in)[i];
    ((half4*)out)[i] = __builtin_convertvector(v, half4);
}

// ---------------------------------------------------------------------------
// Free-flow pipelined GEMM, 2-blocks/CU, BK=64 (the proven round-8 body).
// C[M,N] = A[M,K] · W[N,K]^T, f16 MFMA, fp32 acc.
// BM=128, BN=128, BK=64, 256 threads = 4 waves (2x2), 64x64 per wave.
// 2-buffer LDS ring (64KB -> 2 blocks/CU). ONE s_barrier + ONE vmcnt(0)/tile;
// tile t+1's 8 loads issued right after the barrier, land during a full
// tile of compute. XOR swizzle (granule ^= row&7) on source + ds_read.
// NEW (round 10): 1-D grid, WEIGHT-MAJOR-per-XCD decode — co-resident blocks
// of an XCD share ONE weight panel-pair (1MB, L2-clean) instead of all
// three (6MB > 4MB L2 thrash -> 209MB FETCH). Pure index remap; inner loop
// byte-identical to round 8.
//   QKV (NW=3): grid 1536: xcd=bx&7; seq=bx>>3; m=seq&31; sub=(seq>>5)&1;
//               w=seq>>6; n_tile=xcd*2+sub.
//   Wo  (NW=1): grid 512:  xcd=bx&7; seq=bx>>3; m=seq&31; n_tile=xcd*2+(seq>>5).
#define GBUF (128*64 + 128*64)   // f16 elements per ring buffer (32KB)

__device__ __forceinline__ void stage512(
    const _Float16* __restrict__ gsrc, int ldk,
    _Float16* lbase, int slot0, int wave, int lane)
{
    int slot = slot0 + wave*64 + lane;
    int row  = slot >> 3;
    int sg   = (slot & 7) ^ (row & 7);        // inverse swizzle on source
    async_copy16(gsrc + (size_t)row * ldk + sg * 8,
                 lbase + (slot0 + wave*64) * 8);
}

template<bool BIAS, typename OutT, int NW, bool TRV>
__global__ __launch_bounds__(256, 2) void gemm_bt(
    const _Float16* __restrict__ A,
    const _Float16* __restrict__ W0, const _Float16* __restrict__ W1,
    const _Float16* __restrict__ W2,
    OutT* __restrict__ C0, OutT* __restrict__ C1, OutT* __restrict__ C2,
    const float* __restrict__ bias, int M, int N, int K)
{
    const int bx  = blockIdx.x;
    const int xcd = bx & 7;
    const int seq = bx >> 3;
    int m_tile, n_tile, widx;
    if (NW > 1) {
        m_tile = seq & 31;
        n_tile = xcd * 2 + ((seq >> 5) & 1);
        widx   = seq >> 6;                    // 0..2, rotates per m-sweep
    } else {
        m_tile = seq & 31;
        n_tile = xcd * 2 + (seq >> 5);
        widx   = 0;
    }
    const _Float16* W = W0; OutT* C = C0;
    if (NW > 1) {
        if (widx == 1) { W = W1; C = C1; }
        else if (widx == 2) { W = W2; C = C2; }
    }
    __shared__ __align__(16) _Float16 sm[2 * GBUF];   // 65536 B

    const int tid  = threadIdx.x;
    const int lane = tid & 63;
    const int wave = tid >> 6;                        // 0..3
    const int wm = wave >> 1, wn = wave & 1;          // 2x2 waves, 64x64 each
    const int fr = lane & 15, fg = lane >> 4;

    const int m0 = m_tile * 128;
    const int n0 = n_tile * 128;

    const int NT = K >> 6;                            // K-tiles of 64

    // ---- prologue: stage tile 0 into buf 0 --------------------------------
    {
        _Float16* ab = &sm[0];
        _Float16* bb = ab + 128*64;
        const _Float16* Ag = A + (size_t)m0 * K;
        const _Float16* Wg = W + (size_t)n0 * K;
#pragma unroll
        for (int s0 = 0; s0 < 1024; s0 += 256) {
            stage512(Ag, K, ab, s0, wave, lane);
            stage512(Wg, K, bb, s0, wave, lane);
        }
    }

    floatx4 acc[4][4] = {};

    for (int t = 0; t < NT; ++t) {
        // ---- tile boundary: tile t's 8 loads are the only outstanding ----
        __asm__ __volatile__("s_waitcnt vmcnt(0)" ::: "memory");
        __builtin_amdgcn_sched_barrier(0);
        __builtin_amdgcn_s_barrier();      // t landed; buf[(t+1)&1] reads done
        __builtin_amdgcn_sched_barrier(0);

        const _Float16* Ab = &sm[(t & 1) * GBUF];
        const _Float16* Bb = Ab + 128*64;

        // ---- issue tile t+1 staging first (max in-flight cover) ----------
        if (t + 1 < NT) {
            _Float16* pab = &sm[((t + 1) & 1) * GBUF];
            _Float16* pbb = pab + 128*64;
            const _Float16* pAg = A + (size_t)m0 * K + (t + 1)*64;
            const _Float16* pWg = W + (size_t)n0 * K + (t + 1)*64;
#pragma unroll
            for (int s0 = 0; s0 < 1024; s0 += 256) {
                stage512(pAg, K, pab, s0, wave, lane);
                stage512(pWg, K, pbb, s0, wave, lane);
            }
        }

        // ---- fragment loads (compiler-scheduled, fine-grained lgkmcnt) ---
        half8 af[4][2], bf[4][2];
#pragma unroll
        for (int mt = 0; mt < 4; ++mt)
#pragma unroll
            for (int kk = 0; kk < 2; ++kk) {
                int row = wm*64 + mt*16 + fr;
                int g = (kk*4 + fg) ^ (row & 7);
                af[mt][kk] = *(const half8*)&Ab[row*64 + g*8];
            }
#pragma unroll
        for (int nt = 0; nt < 4; ++nt)
#pragma unroll
            for (int kk = 0; kk < 2; ++kk) {
                int row = wn*64 + nt*16 + fr;
                int g = (kk*4 + fg) ^ (row & 7);
                bf[nt][kk] = *(const half8*)&Bb[row*64 + g*8];
            }

        // ---- 32 MFMA ------------------------------------------------------
        __builtin_amdgcn_s_setprio(1);
#pragma unroll
        for (int kk = 0; kk < 2; ++kk)
#pragma unroll
            for (int nt = 0; nt < 4; ++nt)
#pragma unroll
                for (int mt = 0; mt < 4; ++mt)
                    acc[mt][nt] = __builtin_amdgcn_mfma_f32_16x16x32_f16(
                        af[mt][kk], bf[nt][kk], acc[mt][nt], 0, 0, 0);
        __builtin_amdgcn_s_setprio(0);
    }

    // ---- epilogue ---------------------------------------------------------
    if (TRV && NW > 1 && widx == 2) {
        // write V output directly as Vt[bh][d][s]; r-values are s-contiguous
        _Float16* Vt = (_Float16*)C;
#pragma unroll
        for (int mt = 0; mt < 4; ++mt)
#pragma unroll
            for (int nt = 0; nt < 4; ++nt) {
                int col  = n0 + wn*64 + nt*16 + fr;       // h*128 + d
                int row0 = m0 + wm*64 + mt*16 + fg*4;     // b*2048 + s
                int bq = row0 >> 11, s0 = row0 & 2047;
                int hq = col >> 7,  dq = col & 127;
                half4 v;
#pragma unroll
                for (int r = 0; r < 4; ++r) v[r] = (_Float16)acc[mt][nt][r];
                *(half4*)&Vt[(((size_t)(bq*16 + hq) * 128 + dq) << 11) + s0] = v;
            }
    } else {
        const float qs = (NW > 1 && widx == 0) ? QSCALE : 1.f;
#pragma unroll
        for (int mt = 0; mt < 4; ++mt)
#pragma unroll
            for (int nt = 0; nt < 4; ++nt) {
                int col = n0 + wn*64 + nt*16 + fr;
                float bv = BIAS ? bias[col] : 0.f;
#pragma unroll
                for (int r = 0; r < 4; ++r) {
                    int row = m0 + wm*64 + mt*16 + fg*4 + r;
                    C[(size_t)row * N + col] = (OutT)(acc[mt][nt][r] * qs + bv);
                }
            }
    }
}

// ---------------------------------------------------------------------------
// Block-cooperative causal flash attention (round-8 version, unchanged —
// the best-measured variant). Complementary co-residency: pairs (j, 15-j)
// share a CU -> per-CU fixed cost uniform at 49 iteration-units.
__global__ __launch_bounds__(256, 2) void attn_causal_coop(
    const _Float16* __restrict__ Q, const _Float16* __restrict__ K,
    const _Float16* __restrict__ Vt, _Float16* __restrict__ O)
{
    const int n   = blockIdx.x;
    const int xcd = n & 7;
    const int idx = n >> 3;                    // 0..63
    const int bh  = xcd * 4 + (idx >> 4);      // 4 heads per XCD
    const int j0  = idx & 15;
    const int j   = (idx >> 5) ? 15 - j0 : j0; // complementary pairing
    const int b = bh >> 4, h = bh & 15;
    const int tid = threadIdx.x, lane = tid & 63, wave = tid >> 6;
    const int fr = lane & 15, fg = lane >> 4;

    __shared__ __align__(16) _Float16 Ks[2][64*128];  // 32KB, swizzled, dbuf
    __shared__ __align__(16) _Float16 Vs[2][128*64];  // 32KB, swizzled, dbuf
    __shared__ __align__(16) _Float16 Ps[4][32*64];   // 16KB, swizzled strips

    const int rhi = (31 - j) * 64 + wave * 16;   // this wave's hi-panel rows
    const int rlo = j * 64 + wave * 16;          // this wave's lo-panel rows
    const int nkt = 32 - j;                      // k-tiles of 64

    // Q fragments: A[m=fr][k=fg*8+..], mt: 0=hi panel, 1=lo panel
    half8 qf[2][4];
    {
        const _Float16* qb0 = Q + ((size_t)(b*S_) + rhi) * E_ + h*D_;
        const _Float16* qb1 = Q + ((size_t)(b*S_) + rlo) * E_ + h*D_;
#pragma unroll
        for (int kk = 0; kk < 4; ++kk) {
            qf[0][kk] = *(const half8*)&qb0[(size_t)fr * E_ + kk*32 + fg*8];
            qf[1][kk] = *(const half8*)&qb1[(size_t)fr * E_ + kk*32 + fg*8];
        }
    }

    float m_i[2][4], l_i[2][4];
    floatx4 o[2][8] = {};
#pragma unroll
    for (int mt = 0; mt < 2; ++mt)
#pragma unroll
        for (int r = 0; r < 4; ++r) { m_i[mt][r] = -INFINITY; l_i[mt][r] = 0.f; }

    const _Float16* kg = K + (size_t)(b*S_) * E_ + h*D_;
    const _Float16* vg = Vt + (size_t)bh * D_ * S_;
    _Float16* ps = &Ps[wave][0];

    // ---- prologue: stage K[0], V[0] into buffer 0 -------------------------
#pragma unroll
    for (int q = 0; q < 4; ++q) {
        int G = q*256 + tid;
        { int row = G >> 4, slot = G & 15;
          int c = slot ^ (row & 7);
          async_copy16(kg + (size_t)row * E_ + c*8, &Ks[0][(q*256 + wave*64) * 8]); }
        { int row = G >> 3, slot = G & 7;
          int c = slot ^ (row & 7);
          async_copy16(vg + (size_t)row * S_ + c*8, &Vs[0][(q*256 + wave*64) * 8]); }
    }

    for (int jt = 0; jt < nkt; ++jt) {
        // ---- tile top: own jt loads landed; barrier makes all visible ----
        __asm__ __volatile__("s_waitcnt vmcnt(0)" ::: "memory");
        __builtin_amdgcn_sched_barrier(0);
        __builtin_amdgcn_s_barrier();
        __builtin_amdgcn_sched_barrier(0);

        const int cur = jt & 1, nxt = cur ^ 1;

        // ---- issue jt+1 staging (in flight across the whole tile) --------
        if (jt + 1 < nkt) {
#pragma unroll
            for (int q = 0; q < 4; ++q) {
                int G = q*256 + tid;
                { int row = G >> 4, slot = G & 15;
                  int c = slot ^ (row & 7);
                  async_copy16(kg + (size_t)((jt+1)*64 + row) * E_ + c*8,
                               &Ks[nxt][(q*256 + wave*64) * 8]); }
                { int row = G >> 3, slot = G & 7;
                  int c = slot ^ (row & 7);
                  async_copy16(vg + (size_t)row * S_ + (jt+1)*64 + c*8,
                               &Vs[nxt][(q*256 + wave*64) * 8]); }
            }
        }

        const bool lo_act = (jt <= j);
        const _Float16* kt = &Ks[cur][0];
        const _Float16* vt = &Vs[cur][0];

        // ---- S = Q K^T (log2-domain logits: Q carries 1/sqrt(D)*log2e) ---
        floatx4 sacc[2][4] = {};
#pragma unroll
        for (int kk = 0; kk < 4; ++kk) {
            half8 bf[4];
#pragma unroll
            for (int nt = 0; nt < 4; ++nt)
                bf[nt] = *(const half8*)
                    &kt[(nt*16 + fr)*128 + (((kk*4 + fg) ^ (fr & 7)) * 8)];
#pragma unroll
            for (int nt = 0; nt < 4; ++nt)
                sacc[0][nt] = __builtin_amdgcn_mfma_f32_16x16x32_f16(
                    qf[0][kk], bf[nt], sacc[0][nt], 0, 0, 0);
            if (lo_act) {
#pragma unroll
                for (int nt = 0; nt < 4; ++nt)
                    sacc[1][nt] = __builtin_amdgcn_mfma_f32_16x16x32_f16(
                        qf[1][kk], bf[nt], sacc[1][nt], 0, 0, 0);
            }
        }

        // ---- online softmax (log2 domain, DPP reductions, defer-max) -----
        const int kc0 = jt*64 + fr;
#pragma unroll
        for (int mt = 0; mt < 2; ++mt) {
            if (mt == 1 && !lo_act) continue;
            const bool diag = mt ? (jt == j) : (jt == nkt - 1);
            const int qr0 = (mt ? rlo : rhi) + fg*4;
            float mx[4];
#pragma unroll
            for (int r = 0; r < 4; ++r) {
                float m0v;
                if (diag) {
                    m0v = -INFINITY;
#pragma unroll
                    for (int nt = 0; nt < 4; ++nt) {
                        float s = sacc[mt][nt][r];
                        s = (kc0 + nt*16 <= qr0 + r) ? s : -INFINITY;
                        sacc[mt][nt][r] = s;
                        m0v = fmaxf(m0v, s);
                    }
                } else {
                    m0v = fmaxf(fmaxf(sacc[mt][0][r], sacc[mt][1][r]),
                                fmaxf(sacc[mt][2][r], sacc[mt][3][r]));
                }
                mx[r] = row_max16(m0v);
            }
            bool grow = false;
#pragma unroll
            for (int r = 0; r < 4; ++r)
                grow = grow || (mx[r] > m_i[mt][r] + 8.f);
            if (__any(grow)) {                 // rare after warm-up (T13)
                float alpha[4];
#pragma unroll
                for (int r = 0; r < 4; ++r) {
                    float mnew = fmaxf(m_i[mt][r], mx[r]);
                    alpha[r] = (m_i[mt][r] == -INFINITY) ? 0.f
                                                         : fexp2(m_i[mt][r] - mnew);
                    l_i[mt][r] *= alpha[r];
                    m_i[mt][r] = mnew;
                }
#pragma unroll
                for (int dt = 0; dt < 8; ++dt)
#pragma unroll
                    for (int r = 0; r < 4; ++r) o[mt][dt][r] *= alpha[r];
            }
#pragma unroll
            for (int r = 0; r < 4; ++r) {
                float rs = 0.f;
#pragma unroll
                for (int nt = 0; nt < 4; ++nt) {
                    float p = fexp2(sacc[mt][nt][r] - m_i[mt][r]); // <= 2^8
                    sacc[mt][nt][r] = p;
                    rs += p;
                }
                rs = row_sum16(rs);
                l_i[mt][r] += rs;
            }
            // P: C-layout -> A-layout, wave-private swizzled strip
#pragma unroll
            for (int nt = 0; nt < 4; ++nt)
#pragma unroll
                for (int r = 0; r < 4; ++r) {
                    int q  = mt*16 + fg*4 + r;
                    int gl = nt*2 + (fr >> 3);
                    ps[q*64 + ((gl ^ (q & 7)) << 3) + (fr & 7)]
                        = (_Float16)sacc[mt][nt][r];
                }
        }
        __asm__ __volatile__("s_waitcnt lgkmcnt(0)" ::: "memory");
        __builtin_amdgcn_sched_barrier(0);

        // ---- O += P · V (wave-private P; Vs staged a full tile ago) ------
#pragma unroll
        for (int kk = 0; kk < 2; ++kk) {
            half8 pf0 = *(const half8*)
                &ps[(fr)*64 + (((kk*4 + fg) ^ (fr & 7)) << 3)];
            half8 pf1 = *(const half8*)
                &ps[(16 + fr)*64 + (((kk*4 + fg) ^ (fr & 7)) << 3)];
#pragma unroll
            for (int dt = 0; dt < 8; ++dt) {
                half8 vf = *(const half8*)
                    &vt[(dt*16 + fr)*64 + (((kk*4 + fg) ^ (fr & 7)) * 8)];
                o[0][dt] = __builtin_amdgcn_mfma_f32_16x16x32_f16(
                    pf0, vf, o[0][dt], 0, 0, 0);
                if (lo_act)
                    o[1][dt] = __builtin_amdgcn_mfma_f32_16x16x32_f16(
                        pf1, vf, o[1][dt], 0, 0, 0);
            }
        }
    }

    // ---- epilogue ---------------------------------------------------------
#pragma unroll
    for (int mt = 0; mt < 2; ++mt) {
        const int rbase = mt ? rlo : rhi;
        _Float16* ob = O + ((size_t)(b*S_) + rbase) * E_ + h*D_;
#pragma unroll
        for (int r = 0; r < 4; ++r) {
            float inv = 1.f / l_i[mt][r];
#pragma unroll
            for (int dt = 0; dt < 8; ++dt)
                ob[(size_t)(fg*4 + r) * E_ + dt*16 + fr] = (_Float16)(o[mt][dt][r] * inv);
        }
    }
}

// ---------------------------------------------------------------------------
extern "C" void kernel_launch(void* const* d_in, const int* in_sizes, int n_in,
                              void* d_out, int out_size, void* d_ws, size_t ws_size,
                              hipStream_t stream) {
    const float* X  = (const float*)d_in[0];
    const float* Wq = (const float*)d_in[1];
    const float* Wk = (const float*)d_in[2];
    const float* Wv = (const float*)d_in[3];
    const float* Wo = (const float*)d_in[4];
    const float* bo = (const float*)d_in[5];
    float* out = (float*)d_out;

    const size_t ME = (size_t)M_ * E_;   // 8,388,608
    const size_t EE = (size_t)E_ * E_;   // 4,194,304
    _Float16* ws  = (_Float16*)d_ws;
    _Float16* Xh  = ws;
    _Float16* Wqh = Xh  + ME;
    _Float16* Wkh = Wqh + EE;
    _Float16* Wvh = Wkh + EE;
    _Float16* Woh = Wvh + EE;
    _Float16* Qh  = Woh + EE;
    _Float16* Kh  = Qh  + ME;
    _Float16* Vth = Kh  + ME;   // V-GEMM writes Vt layout directly
    _Float16* Oh  = Xh;         // Xh dead after the QKV GEMMs

    cast_all<<<dim3(4096, 1, 6), dim3(256), 0, stream>>>(
        X, Wq, Wk, Wv, Wo, Xh, Wqh, Wkh, Wvh, Woh);

    gemm_bt<false, _Float16, 3, true><<<dim3(1536), dim3(256), 0, stream>>>(
        Xh, Wqh, Wkh, Wvh, Qh, Kh, Vth, nullptr, M_, E_, E_);

    attn_causal_coop<<<dim3(512), dim3(256), 0, stream>>>(Qh, Kh, Vth, Oh);

    gemm_bt<true, float, 1, false><<<dim3(512), dim3(256), 0, stream>>>(
        Oh, Woh, nullptr, nullptr, out, nullptr, nullptr, bo, M_, E_, E_);
}